// Round 1
// baseline (204.944 us; speedup 1.0000x reference)
//
#include <hip/hip_runtime.h>

// Reference dataflow analysis (unchanged from prior session):
//   step() returns (C_new, H0) -> scan outputs = H0 tiled T times
//   reference returns (outputs, H0) -> all gate math is DEAD CODE
// So d_out = H0 tiled (T+1)=513 times. Pure write-BW problem:
// 134.5 MB writes, 256 KB reads (cache-resident).
//
// This version: register-reuse tiling. Slot i and i+16384 are identical,
// so each thread loads its h0 float4 ONCE and stores it to ~NT/TG tile
// replicas. 16x fewer loads + store loop is register-fed (like the
// harness's fillBufferAligned, which demonstrates 6.8 TB/s write rate).

#define TILE_SLOTS 16384   // float4 slots per H0 tile (128*512 floats / 4)
#define SLOT_MASK  16383
#define TG         32      // tile-groups (blocks striding over tile index)

__global__ void __launch_bounds__(256) tile_h0_kernel(
    const float4* __restrict__ h0, float4* __restrict__ out,
    int n_tiles, int rem_slots) {
  // grid = TG tile-groups x 64 source-chunks; 64 chunks * 256 thr = 16384 slots
  const int chunk = blockIdx.x & 63;
  const int tg    = blockIdx.x >> 6;
  const int slot  = (chunk << 8) + threadIdx.x;   // [0, 16384)

  const float4 v = h0[slot];                      // one load, L1/L2-resident

  // Each block streams its 4KB source chunk to tiles tg, tg+TG, tg+2*TG, ...
  // Every store instruction = 64 lanes x 16B = 1KB coalesced burst.
  for (int tile = tg; tile < n_tiles; tile += TG) {
    out[(size_t)tile * TILE_SLOTS + slot] = v;
  }
  // Tail tile if slot count isn't a multiple of TILE_SLOTS (it is, but be safe).
  if (tg == 0 && slot < rem_slots) {
    out[(size_t)n_tiles * TILE_SLOTS + slot] = v;
  }
}

extern "C" void kernel_launch(void* const* d_in, const int* in_sizes, int n_in,
                              void* d_out, int out_size, void* d_ws, size_t ws_size,
                              hipStream_t stream) {
  // Input order: inputs, H0, C0, W_xi, b_xi, W_hi, b_hi, ... (dict order)
  const float* H0 = (const float*)d_in[1];

  // IDENTICAL write coverage to the prior harness-verified kernel:
  // n4 = out_size/4 float4 slots.
  const int n4      = out_size / 4;
  const int n_tiles = n4 >> 14;          // full H0 tiles
  const int rem     = n4 & SLOT_MASK;    // leftover slots (expected 0)

  const int block = 256;
  const int grid  = 64 * TG;             // 2048 blocks, ~16 stores/thread

  tile_h0_kernel<<<grid, block, 0, stream>>>(
      (const float4*)H0, (float4*)d_out, n_tiles, rem);
}

// Round 3
// 202.161 us; speedup vs baseline: 1.0138x; 1.0138x over previous
//
#include <hip/hip_runtime.h>

// Reference dataflow analysis (unchanged):
//   step() returns (C_new, H0) -> scan outputs = H0 tiled T times
//   reference returns (outputs, H0) -> all gate math is DEAD CODE
// So d_out = H0 tiled (T+1)=513 times. Pure write-BW problem:
// 134.5 MB writes, 256 KB reads (L2-resident).
//
// Round-2 post-mortem: compile error only — __builtin_nontemporal_store
// needs a NATIVE clang vector type, not HIP_vector_type<float,4>.
// Theory under test (from r1) is unchanged: streaming 134.5 MB through
// the 32 MB L2 write-allocates and throttles vs the fill kernel's
// 6.7 TB/s; nontemporal (nt) stores + register-fed store loop fix it.

typedef float fvec4 __attribute__((ext_vector_type(4)));  // native vec: nt-store OK

#define TILE_SLOTS 16384   // fvec4 slots per H0 tile (128*512 floats / 4)
#define SLOT_MASK  16383
#define TG         64      // tile-groups -> ~8 stores/thread over 513 tiles

__global__ void __launch_bounds__(256) tile_h0_kernel(
    const fvec4* __restrict__ h0, fvec4* __restrict__ out,
    int n_tiles, int rem_slots) {
  // grid = TG tile-groups x 64 source-chunks = 4096 blocks (16/CU).
  const int chunk = blockIdx.x & 63;
  const int tg    = blockIdx.x >> 6;
  const int slot  = (chunk << 8) + threadIdx.x;   // [0, 16384)

  const fvec4 v = h0[slot];                       // one load, L2-resident

  // Stream the 4KB source chunk to tiles tg, tg+TG, ... as nontemporal
  // (L2-bypass) stores. Each store = 64 lanes x 16B = 1KB coalesced burst.
  for (int tile = tg; tile < n_tiles; tile += TG) {
    __builtin_nontemporal_store(v, &out[(size_t)tile * TILE_SLOTS + slot]);
  }
  // Generic tail if total slots aren't a multiple of TILE_SLOTS (they are).
  if (tg == 0 && slot < rem_slots) {
    __builtin_nontemporal_store(v, &out[(size_t)n_tiles * TILE_SLOTS + slot]);
  }
}

extern "C" void kernel_launch(void* const* d_in, const int* in_sizes, int n_in,
                              void* d_out, int out_size, void* d_ws, size_t ws_size,
                              hipStream_t stream) {
  // Input order: inputs, H0, C0, W_xi, b_xi, W_hi, b_hi, ... (dict order)
  const float* H0 = (const float*)d_in[1];

  // IDENTICAL write coverage to the harness-verified kernels:
  // n4 = out_size/4 float4 slots.
  const int n4      = out_size / 4;
  const int n_tiles = n4 >> 14;          // full H0 tiles (513)
  const int rem     = n4 & SLOT_MASK;    // leftover slots (expected 0)

  const int block = 256;
  const int grid  = 64 * TG;             // 4096 blocks, ~8 stores/thread

  tile_h0_kernel<<<grid, block, 0, stream>>>(
      (const fvec4*)H0, (fvec4*)d_out, n_tiles, rem);
}

// Round 4
// 196.404 us; speedup vs baseline: 1.0435x; 1.0293x over previous
//
#include <hip/hip_runtime.h>

// Reference dataflow analysis:
//   step() returns (C_new, H0)  -> scan outputs = H0 tiled T times
//   reference returns (outputs, H0) -> C_final and all gate math are DEAD CODE
// So d_out = [H0 repeated T times][H0] == H0 tiled (T+1)=513 times.
// Pure write-BW problem: 134.5 MB writes, 256 KB reads (L2-resident).
//
// Optimization ladder post-mortem (r0-r3):
//   r0: one coalesced float4 store/thread ............ residual 36.6 us (BEST)
//   r1: 1 load + 16 register-fed stores/thread ....... residual ~38 us (neutral)
//   r3: nontemporal (L2-bypass) stores ............... residual 43.6 us (WORSE -7us)
// Conclusion: L2 write-combining HELPS the stream (nt regression refutes the
// write-allocate-pollution theory); the one-shot structure is at the write
// roofline demonstrated by the harness's own fillBufferAligned (6.8 TB/s).
// This is r0 restored — the best harness-verified kernel.

// B*H = 128*512 = 65536 floats = 16384 float4. Power of two -> mask.
#define SRC_MASK4 16383

__global__ void __launch_bounds__(256) tile_h0_kernel(
    const float4* __restrict__ h0, float4* __restrict__ out, int n4) {
  int i = blockIdx.x * blockDim.x + threadIdx.x;
  if (i < n4) {
    out[i] = h0[i & SRC_MASK4];
  }
}

extern "C" void kernel_launch(void* const* d_in, const int* in_sizes, int n_in,
                              void* d_out, int out_size, void* d_ws, size_t ws_size,
                              hipStream_t stream) {
  // Input order: inputs, H0, C0, W_xi, b_xi, W_hi, b_hi, ... (dict order)
  const float* H0 = (const float*)d_in[1];

  int n4 = out_size / 4;  // 33,619,968 / 4 = 8,404,992 float4 stores
  const int block = 256;
  int grid = (n4 + block - 1) / block;

  tile_h0_kernel<<<grid, block, 0, stream>>>(
      (const float4*)H0, (float4*)d_out, n4);
}